// Round 11
// baseline (2753.821 us; speedup 1.0000x reference)
//
#include <hip/hip_runtime.h>

#define NPTS 40000
#define NEDGE 1000000
#define BN_EPS 1e-5f

// ===========================================================================
// Edge geometry: validity + cell + factorized weights.
// ew4 = (wx0, wx1, fy, 0) with wx0=(1-fx)*win, wx1=fx*win.
// ===========================================================================
__device__ inline bool edge_geom(const float* rel_pos, const int* ws_ptr, int e,
                                 int& cell, float4& w4) {
    float ws = (float)ws_ptr[0];
    float inv_ws = 1.0f / ws;
    float ux = rel_pos[2 * e] * inv_ws;
    float uy = rel_pos[2 * e + 1] * inv_ws;
    float q = 1.0f - (ux * ux + uy * uy);
    if (!(q > 0.0f)) return false;
    float win = q * q * q;
    float gx = fminf(fmaxf((ux + 1.0f) * 1.5f, 0.0f), 3.0f);
    float gy = fminf(fmaxf((uy + 1.0f) * 1.5f, 0.0f), 3.0f);
    int ix = (int)floorf(gx); ix = ix < 0 ? 0 : (ix > 2 ? 2 : ix);
    int iy = (int)floorf(gy); iy = iy < 0 ? 0 : (iy > 2 ? 2 : iy);
    float fx = gx - (float)ix;
    float fy = gy - (float)iy;
    cell = ix * 4 + iy;
    w4 = make_float4((1.f - fx) * win, fx * win, fy, 0.f);
    return true;
}

__global__ void hist_kernel(const float* __restrict__ rel_pos,
                            const int* __restrict__ receivers,
                            const int* __restrict__ ws_ptr,
                            int* __restrict__ cnt) {
    int e = blockIdx.x * blockDim.x + threadIdx.x;
    if (e >= NEDGE) return;
    int cell; float4 w4;
    if (edge_geom(rel_pos, ws_ptr, e, cell, w4))
        atomicAdd(&cnt[receivers[e]], 1);
}

// one block, 1024 threads: exclusive scan of 40000 counts -> rowptr[40001]
__global__ __launch_bounds__(1024) void scan_kernel(const int* __restrict__ cnt,
                                                    int* __restrict__ rowptr) {
    __shared__ int part[1024];
    int t = threadIdx.x;
    const int CHUNK = 40;  // 1000 threads * 40 = 40000
    int base = t * CHUNK;
    int s = 0;
    if (t < 1000)
        for (int i = 0; i < CHUNK; ++i) s += cnt[base + i];
    part[t] = s;
    __syncthreads();
    for (int off = 1; off < 1024; off <<= 1) {
        int v = (t >= off) ? part[t - off] : 0;
        __syncthreads();
        part[t] += v;
        __syncthreads();
    }
    int excl = (t == 0) ? 0 : part[t - 1];
    if (t < 1000) {
        int run = excl;
        for (int i = 0; i < CHUNK; ++i) { rowptr[base + i] = run; run += cnt[base + i]; }
        if (t == 999) rowptr[NPTS] = run;
    }
}

__global__ void fill_kernel(const float* __restrict__ rel_pos,
                            const int* __restrict__ receivers,
                            const int* __restrict__ senders,
                            const int* __restrict__ ws_ptr,
                            const int* __restrict__ rowptr,
                            int* __restrict__ cursor,
                            int2* __restrict__ sc,
                            float4* __restrict__ ew4) {
    int e = blockIdx.x * blockDim.x + threadIdx.x;
    if (e >= NEDGE) return;
    int cell; float4 w4;
    if (!edge_geom(rel_pos, ws_ptr, e, cell, w4)) return;
    int recv = receivers[e];
    int pos = rowptr[recv] + atomicAdd(&cursor[recv], 1);
    sc[pos] = make_int2(senders[e], cell);
    ew4[pos] = w4;
}

// xa = concat([x, y], axis=-1)  -> [N, 64]
__global__ void build_xa_kernel(const float* __restrict__ x,
                                const float* __restrict__ y,
                                float* __restrict__ xa) {
    int t = blockIdx.x * blockDim.x + threadIdx.x;
    if (t >= NPTS * 64) return;
    int n = t >> 6, c = t & 63;
    xa[t] = (c < 32) ? x[n * 32 + c] : y[n * 32 + (c - 32)];
}

// ===========================================================================
// Per-edge register accumulation (unchanged).
// ===========================================================================
template <int CIN, int VEC>
__device__ __forceinline__ void do_edge(bool act, int e,
                                        const int2* __restrict__ sc,
                                        const float4* __restrict__ ew4,
                                        const float* __restrict__ feat,
                                        int q, float acc[16][VEC]) {
    int2 rec = sc[e];
    float4 w = ew4[e];
    int sender = act ? rec.x : 0;
    float wx0 = act ? w.x : 0.f;
    float wx1 = act ? w.y : 0.f;
    float fy = w.z;
    int ix = rec.y >> 2, iy = rec.y & 3;
    float wy0 = 1.f - fy, wy1 = fy;
    float wxv[4], wyv[4];
#pragma unroll
    for (int c = 0; c < 4; ++c) {
        wxv[c] = (c == ix) ? wx0 : ((c == ix + 1) ? wx1 : 0.f);
        wyv[c] = (c == iy) ? wy0 : ((c == iy + 1) ? wy1 : 0.f);
    }
    float f[VEC];
    const float* fp = feat + (size_t)sender * CIN + q * VEC;
    if constexpr (VEC == 4) {
        float4 v = *(const float4*)fp;
        f[0] = v.x; f[1] = v.y; f[2] = v.z; f[3] = v.w;
    } else {
        float2 v = *(const float2*)fp;
        f[0] = v.x; f[1] = v.y;
    }
#pragma unroll
    for (int cx = 0; cx < 4; ++cx) {
        float wxc = wxv[cx];
#pragma unroll
        for (int cy = 0; cy < 4; ++cy) {
            float wc = wxc * wyv[cy];
#pragma unroll
            for (int j = 0; j < VEC; ++j)
                acc[cx * 4 + cy][j] = fmaf(wc, f[j], acc[cx * 4 + cy][j]);
        }
    }
}

// write cells [P*4, P*4+4) into quarter-size S (static indices only)
template <int P, int CIN>
__device__ __forceinline__ void write_chunk(float* __restrict__ S,
                                            const float acc[16][CIN / 16],
                                            int rloc, int q) {
    constexpr int VEC = CIN / 16;
    constexpr int LDMQ = 4 * CIN + 4;
    float* srow = S + rloc * LDMQ + q * VEC;
#pragma unroll
    for (int c = 0; c < 4; ++c) {
        float* p = srow + c * CIN;
        if constexpr (VEC == 4)
            *(float4*)p = make_float4(acc[P * 4 + c][0], acc[P * 4 + c][1],
                                      acc[P * 4 + c][2], acc[P * 4 + c][3]);
        else
            *(float2*)p = make_float2(acc[P * 4 + c][0], acc[P * 4 + c][1]);
    }
}

// K-split GEMM pass over global m in [P*MQ, (P+1)*MQ); S holds that chunk.
template <int P, int CIN, int COUT>
__device__ __forceinline__ void gemm_pass(const float* __restrict__ W,
                                          const float* __restrict__ S,
                                          int wave, int rowg, int colg,
                                          float racc[4][COUT / 16]) {
    constexpr int MQ = 4 * CIN;
    constexpr int LDMQ = MQ + 4;
    constexpr int KSL4 = MQ / 4;      // K-slice per wave per pass
    constexpr int CT = COUT / 16;
    const float* wp = W + (size_t)(P * MQ + wave * KSL4) * COUT + colg * CT;
    const int mb = wave * KSL4;
#pragma unroll 2
    for (int mm = 0; mm < KSL4; mm += 4) {
        float wreg[4][CT];
#pragma unroll
        for (int u = 0; u < 4; ++u) {
            if constexpr (CT == 4) {
                float4 w4 = *(const float4*)(wp + (size_t)(mm + u) * COUT);
                wreg[u][0] = w4.x; wreg[u][1] = w4.y; wreg[u][2] = w4.z; wreg[u][3] = w4.w;
            } else {
                float2 w2 = *(const float2*)(wp + (size_t)(mm + u) * COUT);
                wreg[u][0] = w2.x; wreg[u][1] = w2.y;
            }
        }
        float4 sv[4];
#pragma unroll
        for (int i = 0; i < 4; ++i)
            sv[i] = *(const float4*)&S[(rowg * 4 + i) * LDMQ + mb + mm];
#pragma unroll
        for (int u = 0; u < 4; ++u) {
#pragma unroll
            for (int i = 0; i < 4; ++i) {
                float s = (&sv[i].x)[u];
#pragma unroll
                for (int j = 0; j < CT; ++j)
                    racc[i][j] = fmaf(s, wreg[u][j], racc[i][j]);
            }
        }
    }
}

// ===========================================================================
// Fused cconv layer. Phase 1: register accumulation. Phase 2: FOUR quarter-K
// chunks (cells 12..15 first, freeing registers progressively) + K-split
// GEMM per chunk; LDS 16.6KB -> 8 blocks/CU (launch_bounds(256,8), VGPR<=64).
// Pair-tree reduction scratch overlays S after its last read.
// ===========================================================================
template <int CIN, int COUT>
__global__ __launch_bounds__(256, 8) void fused_layer(const float* __restrict__ feat,
                                                      const int2* __restrict__ sc,
                                                      const float4* __restrict__ ew4,
                                                      const int* __restrict__ rowptr,
                                                      const float* __restrict__ W,
                                                      const float* __restrict__ a,
                                                      float* __restrict__ P) {
    constexpr int RB = 16;            // receivers per block
    constexpr int MQ = 4 * CIN;       // quarter-K
    constexpr int LDMQ = MQ + 4;
    constexpr int VEC = CIN / 16;
    constexpr int CT = COUT / 16;
    __shared__ float S[RB * LDMQ];    // quarter-K staging; reused as reduction R

    int tid = threadIdx.x;
    int lane = tid & 63;
    int wave = tid >> 6;
    int slot = lane >> 4;
    int q = lane & 15;
    int rloc = wave * 4 + slot;
    int rglob = blockIdx.x * RB + rloc;
    int rs = rowptr[rglob];
    int deg = rowptr[rglob + 1] - rs;
    int md = deg;
    md = max(md, __shfl_xor(md, 16));
    md = max(md, __shfl_xor(md, 32));

    float acc[16][VEC];
#pragma unroll
    for (int cc = 0; cc < 16; ++cc)
#pragma unroll
        for (int j = 0; j < VEC; ++j) acc[cc][j] = 0.f;

#pragma unroll 2
    for (int k = 0; k < md; ++k) {
        bool act = k < deg;
        do_edge<CIN, VEC>(act, rs + (act ? k : 0), sc, ew4, feat, q, acc);
    }

    int rowg = (tid >> 4) & 3;        // 4 row-groups (4 rows each)
    int colg = tid & 15;              // 16 col-groups (CT cols each)
    float racc[4][CT];
#pragma unroll
    for (int i = 0; i < 4; ++i)
#pragma unroll
        for (int j = 0; j < CT; ++j) racc[i][j] = 0.f;

    // --- four quarter-K chunks, high cells first (frees acc progressively) ---
    write_chunk<3, CIN>(S, acc, rloc, q);
    __syncthreads();
    gemm_pass<3, CIN, COUT>(W, S, wave, rowg, colg, racc);
    __syncthreads();
    write_chunk<2, CIN>(S, acc, rloc, q);
    __syncthreads();
    gemm_pass<2, CIN, COUT>(W, S, wave, rowg, colg, racc);
    __syncthreads();
    write_chunk<1, CIN>(S, acc, rloc, q);
    __syncthreads();
    gemm_pass<1, CIN, COUT>(W, S, wave, rowg, colg, racc);
    __syncthreads();
    write_chunk<0, CIN>(S, acc, rloc, q);
    __syncthreads();
    gemm_pass<0, CIN, COUT>(W, S, wave, rowg, colg, racc);
    __syncthreads();

    // --- pair-tree reduction in S's space: (w0+=w1), (w2+=w3), w0 += w2 ---
    float* R = S;                     // 2*16*COUT floats <= RB*LDMQ
    if (wave == 1 || wave == 3) {
        float* r = &R[(wave >> 1) * 16 * COUT];
#pragma unroll
        for (int i = 0; i < 4; ++i) {
            float* p = r + (rowg * 4 + i) * COUT + colg * CT;
            if constexpr (CT == 4)
                *(float4*)p = make_float4(racc[i][0], racc[i][1], racc[i][2], racc[i][3]);
            else
                *(float2*)p = make_float2(racc[i][0], racc[i][1]);
        }
    }
    __syncthreads();
    if (wave == 0 || wave == 2) {
        const float* r = &R[(wave >> 1) * 16 * COUT];
#pragma unroll
        for (int i = 0; i < 4; ++i)
#pragma unroll
            for (int j = 0; j < CT; ++j)
                racc[i][j] += r[(rowg * 4 + i) * COUT + colg * CT + j];
    }
    __syncthreads();
    if (wave == 2) {
#pragma unroll
        for (int i = 0; i < 4; ++i) {
            float* p = &R[(rowg * 4 + i) * COUT + colg * CT];
            if constexpr (CT == 4)
                *(float4*)p = make_float4(racc[i][0], racc[i][1], racc[i][2], racc[i][3]);
            else
                *(float2*)p = make_float2(racc[i][0], racc[i][1]);
        }
    }
    __syncthreads();
    if (wave == 0) {
#pragma unroll
        for (int i = 0; i < 4; ++i) {
            int n = blockIdx.x * RB + rowg * 4 + i;
            float av = a[n];
            float out[CT];
#pragma unroll
            for (int j = 0; j < CT; ++j)
                out[j] = av * (racc[i][j] + R[(rowg * 4 + i) * COUT + colg * CT + j]);
            float* p = P + (size_t)n * COUT + colg * CT;
            if constexpr (CT == 4)
                *(float4*)p = make_float4(out[0], out[1], out[2], out[3]);
            else
                *(float2*)p = make_float2(out[0], out[1]);
        }
    }
}

// ===========================================================================
// BatchNorm: coalesced two-stage deterministic reduction.
// ===========================================================================
template <int COUT>
__global__ __launch_bounds__(256) void stats_part_kernel(const float* __restrict__ P,
                                                         float* __restrict__ part) {
    constexpr int RR = NPTS / 64;        // 625 rows per block
    constexpr int RSTEP = 256 / COUT;    // rows per iteration
    __shared__ float ls[256], ls2[256];
    int tid = threadIdx.x;
    int d = tid % COUT;
    int rr = tid / COUT;
    int n0 = blockIdx.x * RR;
    int n1 = n0 + RR;
    float s = 0.f, s2 = 0.f;
    for (int n = n0 + rr; n < n1; n += RSTEP) {
        float v = P[(size_t)n * COUT + d];
        s += v;
        s2 += v * v;
    }
    ls[tid] = s; ls2[tid] = s2;
    __syncthreads();
    if (tid < COUT) {
        for (int k = 1; k < RSTEP; ++k) {
            s += ls[tid + k * COUT];
            s2 += ls2[tid + k * COUT];
        }
        part[blockIdx.x * 2 * COUT + d] = s;
        part[blockIdx.x * 2 * COUT + COUT + d] = s2;
    }
}

template <int COUT>
__global__ void finalize_bn_kernel(const float* __restrict__ part,
                                   const float* __restrict__ g,
                                   const float* __restrict__ b,
                                   float* __restrict__ scb) {
    int d = threadIdx.x;
    float s = 0.f, s2 = 0.f;
    for (int k = 0; k < 64; ++k) {
        s += part[k * 2 * COUT + d];
        s2 += part[k * 2 * COUT + COUT + d];
    }
    float mean = s / (float)NPTS;
    float var = s2 / (float)NPTS - mean * mean;
    float inv = rsqrtf(var + BN_EPS);
    float scale = inv * g[d];
    scb[d] = scale;
    scb[COUT + d] = b[d] - mean * scale;
}

template <int COUT>
__global__ void apply_relu_kernel(float* __restrict__ P, const float* __restrict__ scb) {
    int t = blockIdx.x * blockDim.x + threadIdx.x;
    if (t >= NPTS * COUT) return;
    int d = t % COUT;
    float v = P[t] * scb[d] + scb[COUT + d];
    P[t] = fmaxf(v, 0.0f);
}

__global__ void apply_sigmix_kernel(const float* __restrict__ P,
                                    const float* __restrict__ scb,
                                    const float* __restrict__ x,
                                    const float* __restrict__ y,
                                    float* __restrict__ out) {
    int t = blockIdx.x * blockDim.x + threadIdx.x;
    if (t >= NPTS * 32) return;
    int d = t & 31;
    float v = P[t] * scb[d] + scb[32 + d];
    float w = 1.0f / (1.0f + expf(-v));
    out[t] = 2.0f * x[t] * w + 2.0f * y[t] * (1.0f - w);
}

// ===========================================================================
template <int CIN, int COUT>
static void run_layer(const float* feat, const int2* sc, const float4* ew4,
                      const int* rowptr, const float* W, const float* g,
                      const float* b, const float* a, float* part, float* scb,
                      float* P, hipStream_t stream) {
    fused_layer<CIN, COUT><<<NPTS / 16, 256, 0, stream>>>(feat, sc, ew4, rowptr, W, a, P);
    stats_part_kernel<COUT><<<64, 256, 0, stream>>>(P, part);
    finalize_bn_kernel<COUT><<<1, COUT, 0, stream>>>(part, g, b, scb);
}

extern "C" void kernel_launch(void* const* d_in, const int* in_sizes, int n_in,
                              void* d_out, int out_size, void* d_ws, size_t ws_size,
                              hipStream_t stream) {
    const float* x = (const float*)d_in[0];
    const float* y = (const float*)d_in[1];
    const int* senders = (const int*)d_in[2];
    const int* receivers = (const int*)d_in[3];
    const float* rel_pos = (const float*)d_in[4];
    const int* ws_ptr = (const int*)d_in[5];
    const float* a = (const float*)d_in[6];
    const float* W1 = (const float*)d_in[7];
    const float* W2 = (const float*)d_in[8];
    const float* W3 = (const float*)d_in[9];
    const float* W4 = (const float*)d_in[10];
    const float* g1 = (const float*)d_in[11];
    const float* b1 = (const float*)d_in[12];
    const float* g2 = (const float*)d_in[13];
    const float* b2 = (const float*)d_in[14];
    const float* g3 = (const float*)d_in[15];
    const float* b3 = (const float*)d_in[16];
    const float* g4 = (const float*)d_in[17];
    const float* b4 = (const float*)d_in[18];

    char* ws = (char*)d_ws;
    size_t off = 0;
    auto alloc = [&](size_t bytes) -> void* {
        void* p = ws + off;
        off += (bytes + 255) & ~(size_t)255;
        return p;
    };
    int* cnt = (int*)alloc((size_t)NPTS * sizeof(int));
    int* rowptr = (int*)alloc((size_t)(NPTS + 1) * sizeof(int));
    int* cursor = (int*)alloc((size_t)NPTS * sizeof(int));
    int2* sc = (int2*)alloc((size_t)(NEDGE + 4) * sizeof(int2));
    float4* ew4 = (float4*)alloc((size_t)(NEDGE + 4) * sizeof(float4));
    float* xa = (float*)alloc((size_t)NPTS * 64 * sizeof(float));  // also P3
    float* P1 = (float*)alloc((size_t)NPTS * 64 * sizeof(float));
    float* P2 = (float*)alloc((size_t)NPTS * 32 * sizeof(float));  // also P4
    float* xo = (float*)alloc((size_t)NPTS * 32 * sizeof(float));
    float* part = (float*)alloc((size_t)64 * 2 * 64 * sizeof(float));
    float* scb = (float*)alloc(2 * 64 * sizeof(float));
    (void)ws_size; (void)in_sizes; (void)n_in; (void)out_size;

    // --- CSR build (shared by all 4 layers) ---
    hipMemsetAsync(cnt, 0, (size_t)NPTS * sizeof(int), stream);
    hist_kernel<<<(NEDGE + 255) / 256, 256, 0, stream>>>(rel_pos, receivers, ws_ptr, cnt);
    scan_kernel<<<1, 1024, 0, stream>>>(cnt, rowptr);
    hipMemsetAsync(cursor, 0, (size_t)NPTS * sizeof(int), stream);
    fill_kernel<<<(NEDGE + 255) / 256, 256, 0, stream>>>(rel_pos, receivers, senders, ws_ptr,
                                                         rowptr, cursor, sc, ew4);
    build_xa_kernel<<<(NPTS * 64 + 255) / 256, 256, 0, stream>>>(x, y, xa);

    // Layer 1: cconv(xa; W1) -> P1, relu(bn) in place
    run_layer<64, 64>(xa, sc, ew4, rowptr, W1, g1, b1, a, part, scb, P1, stream);
    apply_relu_kernel<64><<<(NPTS * 64 + 255) / 256, 256, 0, stream>>>(P1, scb);

    // Layer 2: cconv(P1; W2) -> P2, sigmoid-mix -> xo
    run_layer<64, 32>(P1, sc, ew4, rowptr, W2, g2, b2, a, part, scb, P2, stream);
    apply_sigmix_kernel<<<(NPTS * 32 + 255) / 256, 256, 0, stream>>>(P2, scb, x, y, xo);

    // Layer 3: cconv(xo; W3) -> xa (reuse), relu(bn) in place
    run_layer<32, 64>(xo, sc, ew4, rowptr, W3, g3, b3, a, part, scb, xa, stream);
    apply_relu_kernel<64><<<(NPTS * 64 + 255) / 256, 256, 0, stream>>>(xa, scb);

    // Layer 4: cconv(xa; W4) -> P2 (reuse), sigmoid-mix -> out
    run_layer<64, 32>(xa, sc, ew4, rowptr, W4, g4, b4, a, part, scb, P2, stream);
    apply_sigmix_kernel<<<(NPTS * 32 + 255) / 256, 256, 0, stream>>>(P2, scb, x, y, (float*)d_out);
}

// Round 13
// 714.917 us; speedup vs baseline: 3.8519x; 3.8519x over previous
//
#include <hip/hip_runtime.h>

#define NPTS 40000
#define NEDGE 1000000
#define BN_EPS 1e-5f

// ===========================================================================
// Edge geometry: validity + cell + factorized weights.
// ew4 = (wx0, wx1, fy, 0) with wx0=(1-fx)*win, wx1=fx*win.
// ===========================================================================
__device__ inline bool edge_geom(const float* rel_pos, const int* ws_ptr, int e,
                                 int& cell, float4& w4) {
    float ws = (float)ws_ptr[0];
    float inv_ws = 1.0f / ws;
    float ux = rel_pos[2 * e] * inv_ws;
    float uy = rel_pos[2 * e + 1] * inv_ws;
    float q = 1.0f - (ux * ux + uy * uy);
    if (!(q > 0.0f)) return false;
    float win = q * q * q;
    float gx = fminf(fmaxf((ux + 1.0f) * 1.5f, 0.0f), 3.0f);
    float gy = fminf(fmaxf((uy + 1.0f) * 1.5f, 0.0f), 3.0f);
    int ix = (int)floorf(gx); ix = ix < 0 ? 0 : (ix > 2 ? 2 : ix);
    int iy = (int)floorf(gy); iy = iy < 0 ? 0 : (iy > 2 ? 2 : iy);
    float fx = gx - (float)ix;
    float fy = gy - (float)iy;
    cell = ix * 4 + iy;
    w4 = make_float4((1.f - fx) * win, fx * win, fy, 0.f);
    return true;
}

__global__ void hist_kernel(const float* __restrict__ rel_pos,
                            const int* __restrict__ receivers,
                            const int* __restrict__ ws_ptr,
                            int* __restrict__ cnt) {
    int e = blockIdx.x * blockDim.x + threadIdx.x;
    if (e >= NEDGE) return;
    int cell; float4 w4;
    if (edge_geom(rel_pos, ws_ptr, e, cell, w4))
        atomicAdd(&cnt[receivers[e]], 1);
}

// one block, 1024 threads: exclusive scan of 40000 counts -> rowptr[40001]
__global__ __launch_bounds__(1024) void scan_kernel(const int* __restrict__ cnt,
                                                    int* __restrict__ rowptr) {
    __shared__ int part[1024];
    int t = threadIdx.x;
    const int CHUNK = 40;  // 1000 threads * 40 = 40000
    int base = t * CHUNK;
    int s = 0;
    if (t < 1000)
        for (int i = 0; i < CHUNK; ++i) s += cnt[base + i];
    part[t] = s;
    __syncthreads();
    for (int off = 1; off < 1024; off <<= 1) {
        int v = (t >= off) ? part[t - off] : 0;
        __syncthreads();
        part[t] += v;
        __syncthreads();
    }
    int excl = (t == 0) ? 0 : part[t - 1];
    if (t < 1000) {
        int run = excl;
        for (int i = 0; i < CHUNK; ++i) { rowptr[base + i] = run; run += cnt[base + i]; }
        if (t == 999) rowptr[NPTS] = run;
    }
}

__global__ void fill_kernel(const float* __restrict__ rel_pos,
                            const int* __restrict__ receivers,
                            const int* __restrict__ senders,
                            const int* __restrict__ ws_ptr,
                            const int* __restrict__ rowptr,
                            int* __restrict__ cursor,
                            int2* __restrict__ sc,
                            float4* __restrict__ ew4) {
    int e = blockIdx.x * blockDim.x + threadIdx.x;
    if (e >= NEDGE) return;
    int cell; float4 w4;
    if (!edge_geom(rel_pos, ws_ptr, e, cell, w4)) return;
    int recv = receivers[e];
    int pos = rowptr[recv] + atomicAdd(&cursor[recv], 1);
    sc[pos] = make_int2(senders[e], cell);
    ew4[pos] = w4;
}

// xa = concat([x, y], axis=-1)  -> [N, 64]
__global__ void build_xa_kernel(const float* __restrict__ x,
                                const float* __restrict__ y,
                                float* __restrict__ xa) {
    int t = blockIdx.x * blockDim.x + threadIdx.x;
    if (t >= NPTS * 64) return;
    int n = t >> 6, c = t & 63;
    xa[t] = (c < 32) ? x[n * 32 + c] : y[n * 32 + (c - 32)];
}

// ===========================================================================
// Per-edge register accumulation (unchanged).
// ===========================================================================
template <int CIN, int VEC>
__device__ __forceinline__ void do_edge(bool act, int e,
                                        const int2* __restrict__ sc,
                                        const float4* __restrict__ ew4,
                                        const float* __restrict__ feat,
                                        int q, float acc[16][VEC]) {
    int2 rec = sc[e];
    float4 w = ew4[e];
    int sender = act ? rec.x : 0;
    float wx0 = act ? w.x : 0.f;
    float wx1 = act ? w.y : 0.f;
    float fy = w.z;
    int ix = rec.y >> 2, iy = rec.y & 3;
    float wy0 = 1.f - fy, wy1 = fy;
    float wxv[4], wyv[4];
#pragma unroll
    for (int c = 0; c < 4; ++c) {
        wxv[c] = (c == ix) ? wx0 : ((c == ix + 1) ? wx1 : 0.f);
        wyv[c] = (c == iy) ? wy0 : ((c == iy + 1) ? wy1 : 0.f);
    }
    float f[VEC];
    const float* fp = feat + (size_t)sender * CIN + q * VEC;
    if constexpr (VEC == 4) {
        float4 v = *(const float4*)fp;
        f[0] = v.x; f[1] = v.y; f[2] = v.z; f[3] = v.w;
    } else {
        float2 v = *(const float2*)fp;
        f[0] = v.x; f[1] = v.y;
    }
#pragma unroll
    for (int cx = 0; cx < 4; ++cx) {
        float wxc = wxv[cx];
#pragma unroll
        for (int cy = 0; cy < 4; ++cy) {
            float wc = wxc * wyv[cy];
#pragma unroll
            for (int j = 0; j < VEC; ++j)
                acc[cx * 4 + cy][j] = fmaf(wc, f[j], acc[cx * 4 + cy][j]);
        }
    }
}

// write cells [P*4, P*4+4) into quarter-size S (static indices only)
template <int P, int CIN>
__device__ __forceinline__ void write_chunk(float* __restrict__ S,
                                            const float acc[16][CIN / 16],
                                            int rloc, int q) {
    constexpr int VEC = CIN / 16;
    constexpr int LDMQ = 4 * CIN + 4;
    float* srow = S + rloc * LDMQ + q * VEC;
#pragma unroll
    for (int c = 0; c < 4; ++c) {
        float* p = srow + c * CIN;
        if constexpr (VEC == 4)
            *(float4*)p = make_float4(acc[P * 4 + c][0], acc[P * 4 + c][1],
                                      acc[P * 4 + c][2], acc[P * 4 + c][3]);
        else
            *(float2*)p = make_float2(acc[P * 4 + c][0], acc[P * 4 + c][1]);
    }
}

// K-split GEMM pass over global m in [P*MQ, (P+1)*MQ); S holds that chunk.
template <int P, int CIN, int COUT>
__device__ __forceinline__ void gemm_pass(const float* __restrict__ W,
                                          const float* __restrict__ S,
                                          int wave, int rowg, int colg,
                                          float racc[4][COUT / 16]) {
    constexpr int MQ = 4 * CIN;
    constexpr int LDMQ = MQ + 4;
    constexpr int KSL4 = MQ / 4;      // K-slice per wave per pass
    constexpr int CT = COUT / 16;
    const float* wp = W + (size_t)(P * MQ + wave * KSL4) * COUT + colg * CT;
    const int mb = wave * KSL4;
#pragma unroll 2
    for (int mm = 0; mm < KSL4; mm += 4) {
        float wreg[4][CT];
#pragma unroll
        for (int u = 0; u < 4; ++u) {
            if constexpr (CT == 4) {
                float4 w4 = *(const float4*)(wp + (size_t)(mm + u) * COUT);
                wreg[u][0] = w4.x; wreg[u][1] = w4.y; wreg[u][2] = w4.z; wreg[u][3] = w4.w;
            } else {
                float2 w2 = *(const float2*)(wp + (size_t)(mm + u) * COUT);
                wreg[u][0] = w2.x; wreg[u][1] = w2.y;
            }
        }
        float4 sv[4];
#pragma unroll
        for (int i = 0; i < 4; ++i)
            sv[i] = *(const float4*)&S[(rowg * 4 + i) * LDMQ + mb + mm];
#pragma unroll
        for (int u = 0; u < 4; ++u) {
#pragma unroll
            for (int i = 0; i < 4; ++i) {
                float s = (&sv[i].x)[u];
#pragma unroll
                for (int j = 0; j < CT; ++j)
                    racc[i][j] = fmaf(s, wreg[u][j], racc[i][j]);
            }
        }
    }
}

// ===========================================================================
// Fused cconv layer. Phase 1: register accumulation. Phase 2: FOUR quarter-K
// chunks (cells 12..15 first, freeing registers progressively) + K-split
// GEMM per chunk; LDS 16.9KB. launch_bounds(256,4): allocator free to use
// 64 VGPR (round-11 lesson: forcing 8 waves/EU -> 32 VGPR -> catastrophic
// scratch spill, 3.5GB/dispatch). HW occupancy = min(LDS 9, VGPR@64 8) = 8.
// ===========================================================================
template <int CIN, int COUT>
__global__ __launch_bounds__(256, 4) void fused_layer(const float* __restrict__ feat,
                                                      const int2* __restrict__ sc,
                                                      const float4* __restrict__ ew4,
                                                      const int* __restrict__ rowptr,
                                                      const float* __restrict__ W,
                                                      const float* __restrict__ a,
                                                      float* __restrict__ P) {
    constexpr int RB = 16;            // receivers per block
    constexpr int MQ = 4 * CIN;       // quarter-K
    constexpr int LDMQ = MQ + 4;
    constexpr int VEC = CIN / 16;
    constexpr int CT = COUT / 16;
    __shared__ float S[RB * LDMQ];    // quarter-K staging; reused as reduction R

    int tid = threadIdx.x;
    int lane = tid & 63;
    int wave = tid >> 6;
    int slot = lane >> 4;
    int q = lane & 15;
    int rloc = wave * 4 + slot;
    int rglob = blockIdx.x * RB + rloc;
    int rs = rowptr[rglob];
    int deg = rowptr[rglob + 1] - rs;
    int md = deg;
    md = max(md, __shfl_xor(md, 16));
    md = max(md, __shfl_xor(md, 32));

    float acc[16][VEC];
#pragma unroll
    for (int cc = 0; cc < 16; ++cc)
#pragma unroll
        for (int j = 0; j < VEC; ++j) acc[cc][j] = 0.f;

#pragma unroll 2
    for (int k = 0; k < md; ++k) {
        bool act = k < deg;
        do_edge<CIN, VEC>(act, rs + (act ? k : 0), sc, ew4, feat, q, acc);
    }

    int rowg = (tid >> 4) & 3;        // 4 row-groups (4 rows each)
    int colg = tid & 15;              // 16 col-groups (CT cols each)
    float racc[4][CT];
#pragma unroll
    for (int i = 0; i < 4; ++i)
#pragma unroll
        for (int j = 0; j < CT; ++j) racc[i][j] = 0.f;

    // --- four quarter-K chunks, high cells first (frees acc progressively) ---
    write_chunk<3, CIN>(S, acc, rloc, q);
    __syncthreads();
    gemm_pass<3, CIN, COUT>(W, S, wave, rowg, colg, racc);
    __syncthreads();
    write_chunk<2, CIN>(S, acc, rloc, q);
    __syncthreads();
    gemm_pass<2, CIN, COUT>(W, S, wave, rowg, colg, racc);
    __syncthreads();
    write_chunk<1, CIN>(S, acc, rloc, q);
    __syncthreads();
    gemm_pass<1, CIN, COUT>(W, S, wave, rowg, colg, racc);
    __syncthreads();
    write_chunk<0, CIN>(S, acc, rloc, q);
    __syncthreads();
    gemm_pass<0, CIN, COUT>(W, S, wave, rowg, colg, racc);
    __syncthreads();

    // --- pair-tree reduction in S's space: (w0+=w1), (w2+=w3), w0 += w2 ---
    float* R = S;                     // 2*16*COUT floats <= RB*LDMQ
    if (wave == 1 || wave == 3) {
        float* r = &R[(wave >> 1) * 16 * COUT];
#pragma unroll
        for (int i = 0; i < 4; ++i) {
            float* p = r + (rowg * 4 + i) * COUT + colg * CT;
            if constexpr (CT == 4)
                *(float4*)p = make_float4(racc[i][0], racc[i][1], racc[i][2], racc[i][3]);
            else
                *(float2*)p = make_float2(racc[i][0], racc[i][1]);
        }
    }
    __syncthreads();
    if (wave == 0 || wave == 2) {
        const float* r = &R[(wave >> 1) * 16 * COUT];
#pragma unroll
        for (int i = 0; i < 4; ++i)
#pragma unroll
            for (int j = 0; j < CT; ++j)
                racc[i][j] += r[(rowg * 4 + i) * COUT + colg * CT + j];
    }
    __syncthreads();
    if (wave == 2) {
#pragma unroll
        for (int i = 0; i < 4; ++i) {
            float* p = &R[(rowg * 4 + i) * COUT + colg * CT];
            if constexpr (CT == 4)
                *(float4*)p = make_float4(racc[i][0], racc[i][1], racc[i][2], racc[i][3]);
            else
                *(float2*)p = make_float2(racc[i][0], racc[i][1]);
        }
    }
    __syncthreads();
    if (wave == 0) {
#pragma unroll
        for (int i = 0; i < 4; ++i) {
            int n = blockIdx.x * RB + rowg * 4 + i;
            float av = a[n];
            float out[CT];
#pragma unroll
            for (int j = 0; j < CT; ++j)
                out[j] = av * (racc[i][j] + R[(rowg * 4 + i) * COUT + colg * CT + j]);
            float* p = P + (size_t)n * COUT + colg * CT;
            if constexpr (CT == 4)
                *(float4*)p = make_float4(out[0], out[1], out[2], out[3]);
            else
                *(float2*)p = make_float2(out[0], out[1]);
        }
    }
}

// ===========================================================================
// BatchNorm: coalesced two-stage deterministic reduction.
// ===========================================================================
template <int COUT>
__global__ __launch_bounds__(256) void stats_part_kernel(const float* __restrict__ P,
                                                         float* __restrict__ part) {
    constexpr int RR = NPTS / 64;        // 625 rows per block
    constexpr int RSTEP = 256 / COUT;    // rows per iteration
    __shared__ float ls[256], ls2[256];
    int tid = threadIdx.x;
    int d = tid % COUT;
    int rr = tid / COUT;
    int n0 = blockIdx.x * RR;
    int n1 = n0 + RR;
    float s = 0.f, s2 = 0.f;
    for (int n = n0 + rr; n < n1; n += RSTEP) {
        float v = P[(size_t)n * COUT + d];
        s += v;
        s2 += v * v;
    }
    ls[tid] = s; ls2[tid] = s2;
    __syncthreads();
    if (tid < COUT) {
        for (int k = 1; k < RSTEP; ++k) {
            s += ls[tid + k * COUT];
            s2 += ls2[tid + k * COUT];
        }
        part[blockIdx.x * 2 * COUT + d] = s;
        part[blockIdx.x * 2 * COUT + COUT + d] = s2;
    }
}

template <int COUT>
__global__ void finalize_bn_kernel(const float* __restrict__ part,
                                   const float* __restrict__ g,
                                   const float* __restrict__ b,
                                   float* __restrict__ scb) {
    int d = threadIdx.x;
    float s = 0.f, s2 = 0.f;
    for (int k = 0; k < 64; ++k) {
        s += part[k * 2 * COUT + d];
        s2 += part[k * 2 * COUT + COUT + d];
    }
    float mean = s / (float)NPTS;
    float var = s2 / (float)NPTS - mean * mean;
    float inv = rsqrtf(var + BN_EPS);
    float scale = inv * g[d];
    scb[d] = scale;
    scb[COUT + d] = b[d] - mean * scale;
}

template <int COUT>
__global__ void apply_relu_kernel(float* __restrict__ P, const float* __restrict__ scb) {
    int t = blockIdx.x * blockDim.x + threadIdx.x;
    if (t >= NPTS * COUT) return;
    int d = t % COUT;
    float v = P[t] * scb[d] + scb[COUT + d];
    P[t] = fmaxf(v, 0.0f);
}

__global__ void apply_sigmix_kernel(const float* __restrict__ P,
                                    const float* __restrict__ scb,
                                    const float* __restrict__ x,
                                    const float* __restrict__ y,
                                    float* __restrict__ out) {
    int t = blockIdx.x * blockDim.x + threadIdx.x;
    if (t >= NPTS * 32) return;
    int d = t & 31;
    float v = P[t] * scb[d] + scb[32 + d];
    float w = 1.0f / (1.0f + expf(-v));
    out[t] = 2.0f * x[t] * w + 2.0f * y[t] * (1.0f - w);
}

// ===========================================================================
template <int CIN, int COUT>
static void run_layer(const float* feat, const int2* sc, const float4* ew4,
                      const int* rowptr, const float* W, const float* g,
                      const float* b, const float* a, float* part, float* scb,
                      float* P, hipStream_t stream) {
    fused_layer<CIN, COUT><<<NPTS / 16, 256, 0, stream>>>(feat, sc, ew4, rowptr, W, a, P);
    stats_part_kernel<COUT><<<64, 256, 0, stream>>>(P, part);
    finalize_bn_kernel<COUT><<<1, COUT, 0, stream>>>(part, g, b, scb);
}

extern "C" void kernel_launch(void* const* d_in, const int* in_sizes, int n_in,
                              void* d_out, int out_size, void* d_ws, size_t ws_size,
                              hipStream_t stream) {
    const float* x = (const float*)d_in[0];
    const float* y = (const float*)d_in[1];
    const int* senders = (const int*)d_in[2];
    const int* receivers = (const int*)d_in[3];
    const float* rel_pos = (const float*)d_in[4];
    const int* ws_ptr = (const int*)d_in[5];
    const float* a = (const float*)d_in[6];
    const float* W1 = (const float*)d_in[7];
    const float* W2 = (const float*)d_in[8];
    const float* W3 = (const float*)d_in[9];
    const float* W4 = (const float*)d_in[10];
    const float* g1 = (const float*)d_in[11];
    const float* b1 = (const float*)d_in[12];
    const float* g2 = (const float*)d_in[13];
    const float* b2 = (const float*)d_in[14];
    const float* g3 = (const float*)d_in[15];
    const float* b3 = (const float*)d_in[16];
    const float* g4 = (const float*)d_in[17];
    const float* b4 = (const float*)d_in[18];

    char* ws = (char*)d_ws;
    size_t off = 0;
    auto alloc = [&](size_t bytes) -> void* {
        void* p = ws + off;
        off += (bytes + 255) & ~(size_t)255;
        return p;
    };
    int* cnt = (int*)alloc((size_t)NPTS * sizeof(int));
    int* rowptr = (int*)alloc((size_t)(NPTS + 1) * sizeof(int));
    int* cursor = (int*)alloc((size_t)NPTS * sizeof(int));
    int2* sc = (int2*)alloc((size_t)(NEDGE + 4) * sizeof(int2));
    float4* ew4 = (float4*)alloc((size_t)(NEDGE + 4) * sizeof(float4));
    float* xa = (float*)alloc((size_t)NPTS * 64 * sizeof(float));  // also P3
    float* P1 = (float*)alloc((size_t)NPTS * 64 * sizeof(float));
    float* P2 = (float*)alloc((size_t)NPTS * 32 * sizeof(float));  // also P4
    float* xo = (float*)alloc((size_t)NPTS * 32 * sizeof(float));
    float* part = (float*)alloc((size_t)64 * 2 * 64 * sizeof(float));
    float* scb = (float*)alloc(2 * 64 * sizeof(float));
    (void)ws_size; (void)in_sizes; (void)n_in; (void)out_size;

    // --- CSR build (shared by all 4 layers) ---
    hipMemsetAsync(cnt, 0, (size_t)NPTS * sizeof(int), stream);
    hist_kernel<<<(NEDGE + 255) / 256, 256, 0, stream>>>(rel_pos, receivers, ws_ptr, cnt);
    scan_kernel<<<1, 1024, 0, stream>>>(cnt, rowptr);
    hipMemsetAsync(cursor, 0, (size_t)NPTS * sizeof(int), stream);
    fill_kernel<<<(NEDGE + 255) / 256, 256, 0, stream>>>(rel_pos, receivers, senders, ws_ptr,
                                                         rowptr, cursor, sc, ew4);
    build_xa_kernel<<<(NPTS * 64 + 255) / 256, 256, 0, stream>>>(x, y, xa);

    // Layer 1: cconv(xa; W1) -> P1, relu(bn) in place
    run_layer<64, 64>(xa, sc, ew4, rowptr, W1, g1, b1, a, part, scb, P1, stream);
    apply_relu_kernel<64><<<(NPTS * 64 + 255) / 256, 256, 0, stream>>>(P1, scb);

    // Layer 2: cconv(P1; W2) -> P2, sigmoid-mix -> xo
    run_layer<64, 32>(P1, sc, ew4, rowptr, W2, g2, b2, a, part, scb, P2, stream);
    apply_sigmix_kernel<<<(NPTS * 32 + 255) / 256, 256, 0, stream>>>(P2, scb, x, y, xo);

    // Layer 3: cconv(xo; W3) -> xa (reuse), relu(bn) in place
    run_layer<32, 64>(xo, sc, ew4, rowptr, W3, g3, b3, a, part, scb, xa, stream);
    apply_relu_kernel<64><<<(NPTS * 64 + 255) / 256, 256, 0, stream>>>(xa, scb);

    // Layer 4: cconv(xa; W4) -> P2 (reuse), sigmoid-mix -> out
    run_layer<64, 32>(xa, sc, ew4, rowptr, W4, g4, b4, a, part, scb, P2, stream);
    apply_sigmix_kernel<<<(NPTS * 32 + 255) / 256, 256, 0, stream>>>(P2, scb, x, y, (float*)d_out);
}

// Round 15
// 710.990 us; speedup vs baseline: 3.8732x; 1.0055x over previous
//
#include <hip/hip_runtime.h>

#define NPTS 40000
#define NEDGE 1000000
#define BN_EPS 1e-5f

// ===========================================================================
// Edge geometry: validity + cell + factorized weights.
// ew4 = (wx0, wx1, fy, 0) with wx0=(1-fx)*win, wx1=fx*win.
// ===========================================================================
__device__ inline bool edge_geom(const float* rel_pos, const int* ws_ptr, int e,
                                 int& cell, float4& w4) {
    float ws = (float)ws_ptr[0];
    float inv_ws = 1.0f / ws;
    float ux = rel_pos[2 * e] * inv_ws;
    float uy = rel_pos[2 * e + 1] * inv_ws;
    float q = 1.0f - (ux * ux + uy * uy);
    if (!(q > 0.0f)) return false;
    float win = q * q * q;
    float gx = fminf(fmaxf((ux + 1.0f) * 1.5f, 0.0f), 3.0f);
    float gy = fminf(fmaxf((uy + 1.0f) * 1.5f, 0.0f), 3.0f);
    int ix = (int)floorf(gx); ix = ix < 0 ? 0 : (ix > 2 ? 2 : ix);
    int iy = (int)floorf(gy); iy = iy < 0 ? 0 : (iy > 2 ? 2 : iy);
    float fx = gx - (float)ix;
    float fy = gy - (float)iy;
    cell = ix * 4 + iy;
    w4 = make_float4((1.f - fx) * win, fx * win, fy, 0.f);
    return true;
}

__global__ void hist_kernel(const float* __restrict__ rel_pos,
                            const int* __restrict__ receivers,
                            const int* __restrict__ ws_ptr,
                            int* __restrict__ cnt) {
    int e = blockIdx.x * blockDim.x + threadIdx.x;
    if (e >= NEDGE) return;
    int cell; float4 w4;
    if (edge_geom(rel_pos, ws_ptr, e, cell, w4))
        atomicAdd(&cnt[receivers[e]], 1);
}

// one block, 1024 threads: exclusive scan of 40000 counts -> rowptr[40001]
__global__ __launch_bounds__(1024) void scan_kernel(const int* __restrict__ cnt,
                                                    int* __restrict__ rowptr) {
    __shared__ int part[1024];
    int t = threadIdx.x;
    const int CHUNK = 40;  // 1000 threads * 40 = 40000
    int base = t * CHUNK;
    int s = 0;
    if (t < 1000)
        for (int i = 0; i < CHUNK; ++i) s += cnt[base + i];
    part[t] = s;
    __syncthreads();
    for (int off = 1; off < 1024; off <<= 1) {
        int v = (t >= off) ? part[t - off] : 0;
        __syncthreads();
        part[t] += v;
        __syncthreads();
    }
    int excl = (t == 0) ? 0 : part[t - 1];
    if (t < 1000) {
        int run = excl;
        for (int i = 0; i < CHUNK; ++i) { rowptr[base + i] = run; run += cnt[base + i]; }
        if (t == 999) rowptr[NPTS] = run;
    }
}

__global__ void fill_kernel(const float* __restrict__ rel_pos,
                            const int* __restrict__ receivers,
                            const int* __restrict__ senders,
                            const int* __restrict__ ws_ptr,
                            const int* __restrict__ rowptr,
                            int* __restrict__ cursor,
                            int2* __restrict__ sc,
                            float4* __restrict__ ew4) {
    int e = blockIdx.x * blockDim.x + threadIdx.x;
    if (e >= NEDGE) return;
    int cell; float4 w4;
    if (!edge_geom(rel_pos, ws_ptr, e, cell, w4)) return;
    int recv = receivers[e];
    int pos = rowptr[recv] + atomicAdd(&cursor[recv], 1);
    sc[pos] = make_int2(senders[e], cell);
    ew4[pos] = w4;
}

// xa = concat([x, y], axis=-1)  -> [N, 64]
__global__ void build_xa_kernel(const float* __restrict__ x,
                                const float* __restrict__ y,
                                float* __restrict__ xa) {
    int t = blockIdx.x * blockDim.x + threadIdx.x;
    if (t >= NPTS * 64) return;
    int n = t >> 6, c = t & 63;
    xa[t] = (c < 32) ? x[n * 32 + c] : y[n * 32 + (c - 32)];
}

// ===========================================================================
// W repack: bf16 (RTN), layout [g][colg][sub] with sub = r*CT + j,
// m = g*MPG + r, col = colg*CT + j, MPG = 8/CT m's per 16B group.
// One 16B load = MPG m's x CT cols for one colg -> halves W traffic at the
// same in-flight byte count (round-13 lesson: GEMM is Little's-law-bound on
// W loads from L2 at 16 waves/CU; can't raise concurrency, so cut bytes).
// ===========================================================================
template <int M, int COUT>
__global__ void pack_w_kernel(const float* __restrict__ W,
                              unsigned short* __restrict__ Wp) {
    constexpr int CT = COUT / 16;
    constexpr int MPG = 8 / CT;
    int idx = blockIdx.x * 256 + threadIdx.x;
    if (idx >= M * COUT) return;
    int g = idx >> 7, colg = (idx >> 3) & 15, sub = idx & 7;
    int r = sub / CT, j = sub % CT;
    int m = g * MPG + r, col = colg * CT + j;
    unsigned u = __float_as_uint(W[(size_t)m * COUT + col]);
    unsigned rounded = (u + 0x7FFFu + ((u >> 16) & 1u)) >> 16;  // RTN-even
    Wp[idx] = (unsigned short)rounded;
}

__device__ __forceinline__ float bflo(unsigned x) { return __uint_as_float(x << 16); }
__device__ __forceinline__ float bfhi(unsigned x) { return __uint_as_float(x & 0xFFFF0000u); }

// ===========================================================================
// Per-edge register accumulation (unchanged).
// ===========================================================================
template <int CIN, int VEC>
__device__ __forceinline__ void do_edge(bool act, int e,
                                        const int2* __restrict__ sc,
                                        const float4* __restrict__ ew4,
                                        const float* __restrict__ feat,
                                        int q, float acc[16][VEC]) {
    int2 rec = sc[e];
    float4 w = ew4[e];
    int sender = act ? rec.x : 0;
    float wx0 = act ? w.x : 0.f;
    float wx1 = act ? w.y : 0.f;
    float fy = w.z;
    int ix = rec.y >> 2, iy = rec.y & 3;
    float wy0 = 1.f - fy, wy1 = fy;
    float wxv[4], wyv[4];
#pragma unroll
    for (int c = 0; c < 4; ++c) {
        wxv[c] = (c == ix) ? wx0 : ((c == ix + 1) ? wx1 : 0.f);
        wyv[c] = (c == iy) ? wy0 : ((c == iy + 1) ? wy1 : 0.f);
    }
    float f[VEC];
    const float* fp = feat + (size_t)sender * CIN + q * VEC;
    if constexpr (VEC == 4) {
        float4 v = *(const float4*)fp;
        f[0] = v.x; f[1] = v.y; f[2] = v.z; f[3] = v.w;
    } else {
        float2 v = *(const float2*)fp;
        f[0] = v.x; f[1] = v.y;
    }
#pragma unroll
    for (int cx = 0; cx < 4; ++cx) {
        float wxc = wxv[cx];
#pragma unroll
        for (int cy = 0; cy < 4; ++cy) {
            float wc = wxc * wyv[cy];
#pragma unroll
            for (int j = 0; j < VEC; ++j)
                acc[cx * 4 + cy][j] = fmaf(wc, f[j], acc[cx * 4 + cy][j]);
        }
    }
}

// write cells [P*4, P*4+4) into quarter-size S (static indices only)
template <int P, int CIN>
__device__ __forceinline__ void write_chunk(float* __restrict__ S,
                                            const float acc[16][CIN / 16],
                                            int rloc, int q) {
    constexpr int VEC = CIN / 16;
    constexpr int LDMQ = 4 * CIN + 4;
    float* srow = S + rloc * LDMQ + q * VEC;
#pragma unroll
    for (int c = 0; c < 4; ++c) {
        float* p = srow + c * CIN;
        if constexpr (VEC == 4)
            *(float4*)p = make_float4(acc[P * 4 + c][0], acc[P * 4 + c][1],
                                      acc[P * 4 + c][2], acc[P * 4 + c][3]);
        else
            *(float2*)p = make_float2(acc[P * 4 + c][0], acc[P * 4 + c][1]);
    }
}

// K-split GEMM pass over global m in [P*MQ, (P+1)*MQ); S holds that chunk.
// W read from bf16 pack: 16B covers MPG m's x CT cols.
template <int P, int CIN, int COUT>
__device__ __forceinline__ void gemm_pass(const unsigned short* __restrict__ Wp,
                                          const float* __restrict__ S,
                                          int wave, int rowg, int colg,
                                          float racc[4][COUT / 16]) {
    constexpr int MQ = 4 * CIN;
    constexpr int LDMQ = MQ + 4;
    constexpr int KSL4 = MQ / 4;      // K-slice per wave per pass
    constexpr int CT = COUT / 16;
    constexpr int MPG = 8 / CT;       // m's per 16B pack group
    const int m0 = P * MQ + wave * KSL4;
    const unsigned short* wbase = Wp + (size_t)(m0 / MPG) * 128 + colg * 8;
    const int mb = wave * KSL4;
#pragma unroll 4
    for (int mm = 0; mm < KSL4; mm += 4) {
        float w[4][CT];
        if constexpr (CT == 4) {
            uint4 pa = *(const uint4*)(wbase + (mm / MPG) * 128);
            uint4 pb = *(const uint4*)(wbase + (mm / MPG) * 128 + 128);
            w[0][0] = bflo(pa.x); w[0][1] = bfhi(pa.x); w[0][2] = bflo(pa.y); w[0][3] = bfhi(pa.y);
            w[1][0] = bflo(pa.z); w[1][1] = bfhi(pa.z); w[1][2] = bflo(pa.w); w[1][3] = bfhi(pa.w);
            w[2][0] = bflo(pb.x); w[2][1] = bfhi(pb.x); w[2][2] = bflo(pb.y); w[2][3] = bfhi(pb.y);
            w[3][0] = bflo(pb.z); w[3][1] = bfhi(pb.z); w[3][2] = bflo(pb.w); w[3][3] = bfhi(pb.w);
        } else {
            uint4 pa = *(const uint4*)(wbase + (mm / MPG) * 128);
            w[0][0] = bflo(pa.x); w[0][1] = bfhi(pa.x);
            w[1][0] = bflo(pa.y); w[1][1] = bfhi(pa.y);
            w[2][0] = bflo(pa.z); w[2][1] = bfhi(pa.z);
            w[3][0] = bflo(pa.w); w[3][1] = bfhi(pa.w);
        }
        float4 sv[4];
#pragma unroll
        for (int i = 0; i < 4; ++i)
            sv[i] = *(const float4*)&S[(rowg * 4 + i) * LDMQ + mb + mm];
#pragma unroll
        for (int u = 0; u < 4; ++u) {
#pragma unroll
            for (int i = 0; i < 4; ++i) {
                float s = (&sv[i].x)[u];
#pragma unroll
                for (int j = 0; j < CT; ++j)
                    racc[i][j] = fmaf(s, w[u][j], racc[i][j]);
            }
        }
    }
}

// ===========================================================================
// Fused cconv layer. Phase 1: register accumulation. Phase 2: FOUR quarter-K
// chunks + K-split GEMM per chunk with bf16-packed W; LDS 16.9KB.
// launch_bounds(256,4): allocator targets 64 VGPR (r11 lesson: forcing 8
// waves/EU -> 32 VGPR -> catastrophic spill). VGPR=64 -> 16 waves/CU (r13).
// ===========================================================================
template <int CIN, int COUT>
__global__ __launch_bounds__(256, 4) void fused_layer(const float* __restrict__ feat,
                                                      const int2* __restrict__ sc,
                                                      const float4* __restrict__ ew4,
                                                      const int* __restrict__ rowptr,
                                                      const unsigned short* __restrict__ Wp,
                                                      const float* __restrict__ a,
                                                      float* __restrict__ P) {
    constexpr int RB = 16;            // receivers per block
    constexpr int MQ = 4 * CIN;       // quarter-K
    constexpr int LDMQ = MQ + 4;
    constexpr int VEC = CIN / 16;
    constexpr int CT = COUT / 16;
    __shared__ float S[RB * LDMQ];    // quarter-K staging; reused as reduction R

    int tid = threadIdx.x;
    int lane = tid & 63;
    int wave = tid >> 6;
    int slot = lane >> 4;
    int q = lane & 15;
    int rloc = wave * 4 + slot;
    int rglob = blockIdx.x * RB + rloc;
    int rs = rowptr[rglob];
    int deg = rowptr[rglob + 1] - rs;
    int md = deg;
    md = max(md, __shfl_xor(md, 16));
    md = max(md, __shfl_xor(md, 32));

    float acc[16][VEC];
#pragma unroll
    for (int cc = 0; cc < 16; ++cc)
#pragma unroll
        for (int j = 0; j < VEC; ++j) acc[cc][j] = 0.f;

#pragma unroll 2
    for (int k = 0; k < md; ++k) {
        bool act = k < deg;
        do_edge<CIN, VEC>(act, rs + (act ? k : 0), sc, ew4, feat, q, acc);
    }

    int rowg = (tid >> 4) & 3;        // 4 row-groups (4 rows each)
    int colg = tid & 15;              // 16 col-groups (CT cols each)
    float racc[4][CT];
#pragma unroll
    for (int i = 0; i < 4; ++i)
#pragma unroll
        for (int j = 0; j < CT; ++j) racc[i][j] = 0.f;

    // --- four quarter-K chunks, high cells first (frees acc progressively) ---
    write_chunk<3, CIN>(S, acc, rloc, q);
    __syncthreads();
    gemm_pass<3, CIN, COUT>(Wp, S, wave, rowg, colg, racc);
    __syncthreads();
    write_chunk<2, CIN>(S, acc, rloc, q);
    __syncthreads();
    gemm_pass<2, CIN, COUT>(Wp, S, wave, rowg, colg, racc);
    __syncthreads();
    write_chunk<1, CIN>(S, acc, rloc, q);
    __syncthreads();
    gemm_pass<1, CIN, COUT>(Wp, S, wave, rowg, colg, racc);
    __syncthreads();
    write_chunk<0, CIN>(S, acc, rloc, q);
    __syncthreads();
    gemm_pass<0, CIN, COUT>(Wp, S, wave, rowg, colg, racc);
    __syncthreads();

    // --- pair-tree reduction in S's space: (w0+=w1), (w2+=w3), w0 += w2 ---
    float* R = S;                     // 2*16*COUT floats <= RB*LDMQ
    if (wave == 1 || wave == 3) {
        float* r = &R[(wave >> 1) * 16 * COUT];
#pragma unroll
        for (int i = 0; i < 4; ++i) {
            float* p = r + (rowg * 4 + i) * COUT + colg * CT;
            if constexpr (CT == 4)
                *(float4*)p = make_float4(racc[i][0], racc[i][1], racc[i][2], racc[i][3]);
            else
                *(float2*)p = make_float2(racc[i][0], racc[i][1]);
        }
    }
    __syncthreads();
    if (wave == 0 || wave == 2) {
        const float* r = &R[(wave >> 1) * 16 * COUT];
#pragma unroll
        for (int i = 0; i < 4; ++i)
#pragma unroll
            for (int j = 0; j < CT; ++j)
                racc[i][j] += r[(rowg * 4 + i) * COUT + colg * CT + j];
    }
    __syncthreads();
    if (wave == 2) {
#pragma unroll
        for (int i = 0; i < 4; ++i) {
            float* p = &R[(rowg * 4 + i) * COUT + colg * CT];
            if constexpr (CT == 4)
                *(float4*)p = make_float4(racc[i][0], racc[i][1], racc[i][2], racc[i][3]);
            else
                *(float2*)p = make_float2(racc[i][0], racc[i][1]);
        }
    }
    __syncthreads();
    if (wave == 0) {
#pragma unroll
        for (int i = 0; i < 4; ++i) {
            int n = blockIdx.x * RB + rowg * 4 + i;
            float av = a[n];
            float out[CT];
#pragma unroll
            for (int j = 0; j < CT; ++j)
                out[j] = av * (racc[i][j] + R[(rowg * 4 + i) * COUT + colg * CT + j]);
            float* p = P + (size_t)n * COUT + colg * CT;
            if constexpr (CT == 4)
                *(float4*)p = make_float4(out[0], out[1], out[2], out[3]);
            else
                *(float2*)p = make_float2(out[0], out[1]);
        }
    }
}

// ===========================================================================
// BatchNorm: coalesced two-stage deterministic reduction.
// ===========================================================================
template <int COUT>
__global__ __launch_bounds__(256) void stats_part_kernel(const float* __restrict__ P,
                                                         float* __restrict__ part) {
    constexpr int RR = NPTS / 64;        // 625 rows per block
    constexpr int RSTEP = 256 / COUT;    // rows per iteration
    __shared__ float ls[256], ls2[256];
    int tid = threadIdx.x;
    int d = tid % COUT;
    int rr = tid / COUT;
    int n0 = blockIdx.x * RR;
    int n1 = n0 + RR;
    float s = 0.f, s2 = 0.f;
    for (int n = n0 + rr; n < n1; n += RSTEP) {
        float v = P[(size_t)n * COUT + d];
        s += v;
        s2 += v * v;
    }
    ls[tid] = s; ls2[tid] = s2;
    __syncthreads();
    if (tid < COUT) {
        for (int k = 1; k < RSTEP; ++k) {
            s += ls[tid + k * COUT];
            s2 += ls2[tid + k * COUT];
        }
        part[blockIdx.x * 2 * COUT + d] = s;
        part[blockIdx.x * 2 * COUT + COUT + d] = s2;
    }
}

template <int COUT>
__global__ void finalize_bn_kernel(const float* __restrict__ part,
                                   const float* __restrict__ g,
                                   const float* __restrict__ b,
                                   float* __restrict__ scb) {
    int d = threadIdx.x;
    float s = 0.f, s2 = 0.f;
    for (int k = 0; k < 64; ++k) {
        s += part[k * 2 * COUT + d];
        s2 += part[k * 2 * COUT + COUT + d];
    }
    float mean = s / (float)NPTS;
    float var = s2 / (float)NPTS - mean * mean;
    float inv = rsqrtf(var + BN_EPS);
    float scale = inv * g[d];
    scb[d] = scale;
    scb[COUT + d] = b[d] - mean * scale;
}

template <int COUT>
__global__ void apply_relu_kernel(float* __restrict__ P, const float* __restrict__ scb) {
    int t = blockIdx.x * blockDim.x + threadIdx.x;
    if (t >= NPTS * COUT) return;
    int d = t % COUT;
    float v = P[t] * scb[d] + scb[COUT + d];
    P[t] = fmaxf(v, 0.0f);
}

__global__ void apply_sigmix_kernel(const float* __restrict__ P,
                                    const float* __restrict__ scb,
                                    const float* __restrict__ x,
                                    const float* __restrict__ y,
                                    float* __restrict__ out) {
    int t = blockIdx.x * blockDim.x + threadIdx.x;
    if (t >= NPTS * 32) return;
    int d = t & 31;
    float v = P[t] * scb[d] + scb[32 + d];
    float w = 1.0f / (1.0f + expf(-v));
    out[t] = 2.0f * x[t] * w + 2.0f * y[t] * (1.0f - w);
}

// ===========================================================================
template <int CIN, int COUT>
static void run_layer(const float* feat, const int2* sc, const float4* ew4,
                      const int* rowptr, const unsigned short* Wp, const float* g,
                      const float* b, const float* a, float* part, float* scb,
                      float* P, hipStream_t stream) {
    fused_layer<CIN, COUT><<<NPTS / 16, 256, 0, stream>>>(feat, sc, ew4, rowptr, Wp, a, P);
    stats_part_kernel<COUT><<<64, 256, 0, stream>>>(P, part);
    finalize_bn_kernel<COUT><<<1, COUT, 0, stream>>>(part, g, b, scb);
}

extern "C" void kernel_launch(void* const* d_in, const int* in_sizes, int n_in,
                              void* d_out, int out_size, void* d_ws, size_t ws_size,
                              hipStream_t stream) {
    const float* x = (const float*)d_in[0];
    const float* y = (const float*)d_in[1];
    const int* senders = (const int*)d_in[2];
    const int* receivers = (const int*)d_in[3];
    const float* rel_pos = (const float*)d_in[4];
    const int* ws_ptr = (const int*)d_in[5];
    const float* a = (const float*)d_in[6];
    const float* W1 = (const float*)d_in[7];
    const float* W2 = (const float*)d_in[8];
    const float* W3 = (const float*)d_in[9];
    const float* W4 = (const float*)d_in[10];
    const float* g1 = (const float*)d_in[11];
    const float* b1 = (const float*)d_in[12];
    const float* g2 = (const float*)d_in[13];
    const float* b2 = (const float*)d_in[14];
    const float* g3 = (const float*)d_in[15];
    const float* b3 = (const float*)d_in[16];
    const float* g4 = (const float*)d_in[17];
    const float* b4 = (const float*)d_in[18];

    char* ws = (char*)d_ws;
    size_t off = 0;
    auto alloc = [&](size_t bytes) -> void* {
        void* p = ws + off;
        off += (bytes + 255) & ~(size_t)255;
        return p;
    };
    int* cnt = (int*)alloc((size_t)NPTS * sizeof(int));
    int* rowptr = (int*)alloc((size_t)(NPTS + 1) * sizeof(int));
    int* cursor = (int*)alloc((size_t)NPTS * sizeof(int));
    int2* sc = (int2*)alloc((size_t)(NEDGE + 4) * sizeof(int2));
    float4* ew4 = (float4*)alloc((size_t)(NEDGE + 4) * sizeof(float4));
    float* xa = (float*)alloc((size_t)NPTS * 64 * sizeof(float));  // also P3
    float* P1 = (float*)alloc((size_t)NPTS * 64 * sizeof(float));
    float* P2 = (float*)alloc((size_t)NPTS * 32 * sizeof(float));  // also P4
    float* xo = (float*)alloc((size_t)NPTS * 32 * sizeof(float));
    float* part = (float*)alloc((size_t)64 * 2 * 64 * sizeof(float));
    float* scb = (float*)alloc(2 * 64 * sizeof(float));
    unsigned short* Wp1 = (unsigned short*)alloc((size_t)1024 * 64 * 2);
    unsigned short* Wp2 = (unsigned short*)alloc((size_t)1024 * 32 * 2);
    unsigned short* Wp3 = (unsigned short*)alloc((size_t)512 * 64 * 2);
    unsigned short* Wp4 = (unsigned short*)alloc((size_t)1024 * 32 * 2);
    (void)ws_size; (void)in_sizes; (void)n_in; (void)out_size;

    // --- W repacks (independent of pipeline, issue first) ---
    pack_w_kernel<1024, 64><<<(1024 * 64) / 256, 256, 0, stream>>>(W1, Wp1);
    pack_w_kernel<1024, 32><<<(1024 * 32) / 256, 256, 0, stream>>>(W2, Wp2);
    pack_w_kernel<512, 64><<<(512 * 64) / 256, 256, 0, stream>>>(W3, Wp3);
    pack_w_kernel<1024, 32><<<(1024 * 32) / 256, 256, 0, stream>>>(W4, Wp4);

    // --- CSR build (shared by all 4 layers) ---
    hipMemsetAsync(cnt, 0, (size_t)NPTS * sizeof(int), stream);
    hist_kernel<<<(NEDGE + 255) / 256, 256, 0, stream>>>(rel_pos, receivers, ws_ptr, cnt);
    scan_kernel<<<1, 1024, 0, stream>>>(cnt, rowptr);
    hipMemsetAsync(cursor, 0, (size_t)NPTS * sizeof(int), stream);
    fill_kernel<<<(NEDGE + 255) / 256, 256, 0, stream>>>(rel_pos, receivers, senders, ws_ptr,
                                                         rowptr, cursor, sc, ew4);
    build_xa_kernel<<<(NPTS * 64 + 255) / 256, 256, 0, stream>>>(x, y, xa);

    // Layer 1: cconv(xa; W1) -> P1, relu(bn) in place
    run_layer<64, 64>(xa, sc, ew4, rowptr, Wp1, g1, b1, a, part, scb, P1, stream);
    apply_relu_kernel<64><<<(NPTS * 64 + 255) / 256, 256, 0, stream>>>(P1, scb);

    // Layer 2: cconv(P1; W2) -> P2, sigmoid-mix -> xo
    run_layer<64, 32>(P1, sc, ew4, rowptr, Wp2, g2, b2, a, part, scb, P2, stream);
    apply_sigmix_kernel<<<(NPTS * 32 + 255) / 256, 256, 0, stream>>>(P2, scb, x, y, xo);

    // Layer 3: cconv(xo; W3) -> xa (reuse), relu(bn) in place
    run_layer<32, 64>(xo, sc, ew4, rowptr, Wp3, g3, b3, a, part, scb, xa, stream);
    apply_relu_kernel<64><<<(NPTS * 64 + 255) / 256, 256, 0, stream>>>(xa, scb);

    // Layer 4: cconv(xa; W4) -> P2 (reuse), sigmoid-mix -> out
    run_layer<64, 32>(xa, sc, ew4, rowptr, Wp4, g4, b4, a, part, scb, P2, stream);
    apply_sigmix_kernel<<<(NPTS * 32 + 255) / 256, 256, 0, stream>>>(P2, scb, x, y, (float*)d_out);
}

// Round 16
// 519.572 us; speedup vs baseline: 5.3002x; 1.3684x over previous
//
#include <hip/hip_runtime.h>

#define NPTS 40000
#define NEDGE 1000000
#define BN_EPS 1e-5f

typedef short bf16x8 __attribute__((ext_vector_type(8)));
typedef float f32x4 __attribute__((ext_vector_type(4)));

__device__ __forceinline__ unsigned short f2bf(float x) {
    unsigned u = __float_as_uint(x);
    return (unsigned short)((u + 0x7FFFu + ((u >> 16) & 1u)) >> 16);  // RTN-even
}

// ===========================================================================
// Edge geometry: validity + cell + factorized weights.
// ===========================================================================
__device__ inline bool edge_geom(const float* rel_pos, const int* ws_ptr, int e,
                                 int& cell, float4& w4) {
    float ws = (float)ws_ptr[0];
    float inv_ws = 1.0f / ws;
    float ux = rel_pos[2 * e] * inv_ws;
    float uy = rel_pos[2 * e + 1] * inv_ws;
    float q = 1.0f - (ux * ux + uy * uy);
    if (!(q > 0.0f)) return false;
    float win = q * q * q;
    float gx = fminf(fmaxf((ux + 1.0f) * 1.5f, 0.0f), 3.0f);
    float gy = fminf(fmaxf((uy + 1.0f) * 1.5f, 0.0f), 3.0f);
    int ix = (int)floorf(gx); ix = ix < 0 ? 0 : (ix > 2 ? 2 : ix);
    int iy = (int)floorf(gy); iy = iy < 0 ? 0 : (iy > 2 ? 2 : iy);
    float fx = gx - (float)ix;
    float fy = gy - (float)iy;
    cell = ix * 4 + iy;
    w4 = make_float4((1.f - fx) * win, fx * win, fy, 0.f);
    return true;
}

__global__ void hist_kernel(const float* __restrict__ rel_pos,
                            const int* __restrict__ receivers,
                            const int* __restrict__ ws_ptr,
                            int* __restrict__ cnt) {
    int e = blockIdx.x * blockDim.x + threadIdx.x;
    if (e >= NEDGE) return;
    int cell; float4 w4;
    if (edge_geom(rel_pos, ws_ptr, e, cell, w4))
        atomicAdd(&cnt[receivers[e]], 1);
}

// one block, 1024 threads: exclusive scan of 40000 counts -> rowptr[40001]
__global__ __launch_bounds__(1024) void scan_kernel(const int* __restrict__ cnt,
                                                    int* __restrict__ rowptr) {
    __shared__ int part[1024];
    int t = threadIdx.x;
    const int CHUNK = 40;  // 1000 threads * 40 = 40000
    int base = t * CHUNK;
    int s = 0;
    if (t < 1000)
        for (int i = 0; i < CHUNK; ++i) s += cnt[base + i];
    part[t] = s;
    __syncthreads();
    for (int off = 1; off < 1024; off <<= 1) {
        int v = (t >= off) ? part[t - off] : 0;
        __syncthreads();
        part[t] += v;
        __syncthreads();
    }
    int excl = (t == 0) ? 0 : part[t - 1];
    if (t < 1000) {
        int run = excl;
        for (int i = 0; i < CHUNK; ++i) { rowptr[base + i] = run; run += cnt[base + i]; }
        if (t == 999) rowptr[NPTS] = run;
    }
}

__global__ void fill_kernel(const float* __restrict__ rel_pos,
                            const int* __restrict__ receivers,
                            const int* __restrict__ senders,
                            const int* __restrict__ ws_ptr,
                            const int* __restrict__ rowptr,
                            int* __restrict__ cursor,
                            int2* __restrict__ sc,
                            float4* __restrict__ ew4) {
    int e = blockIdx.x * blockDim.x + threadIdx.x;
    if (e >= NEDGE) return;
    int cell; float4 w4;
    if (!edge_geom(rel_pos, ws_ptr, e, cell, w4)) return;
    int recv = receivers[e];
    int pos = rowptr[recv] + atomicAdd(&cursor[recv], 1);
    sc[pos] = make_int2(senders[e], cell);
    ew4[pos] = w4;
}

// xa = concat([x, y], axis=-1)  -> [N, 64]
__global__ void build_xa_kernel(const float* __restrict__ x,
                                const float* __restrict__ y,
                                float* __restrict__ xa) {
    int t = blockIdx.x * blockDim.x + threadIdx.x;
    if (t >= NPTS * 64) return;
    int n = t >> 6, c = t & 63;
    xa[t] = (c < 32) ? x[n * 32 + c] : y[n * 32 + (c - 32)];
}

// ===========================================================================
// W repack into bf16 MFMA B-fragment layout:
// Wp[((cb*nKS + ks)*64 + l)*8 + j] = bf16(W[ks*32 + (l>>4)*8 + j][cb*16 + (l&15)])
// One 16B load per (wave, K-step, lane) = the exact B fragment for
// mfma_f32_16x16x32_bf16 (lane: col=l&15, k=(l>>4)*8+j). Coalesced.
// ===========================================================================
template <int M, int COUT>
__global__ void pack_w_kernel(const float* __restrict__ W,
                              unsigned short* __restrict__ Wp) {
    constexpr int nKS = M / 32;
    int idx = blockIdx.x * 256 + threadIdx.x;
    if (idx >= M * COUT) return;
    int j = idx & 7;
    int l = (idx >> 3) & 63;
    int t = idx >> 9;          // cb*nKS + ks
    int ks = t % nKS;
    int cb = t / nKS;
    int m = ks * 32 + (l >> 4) * 8 + j;
    int col = cb * 16 + (l & 15);
    Wp[idx] = f2bf(W[(size_t)m * COUT + col]);
}

// ===========================================================================
// Per-edge register accumulation (unchanged).
// ===========================================================================
template <int CIN, int VEC>
__device__ __forceinline__ void do_edge(bool act, int e,
                                        const int2* __restrict__ sc,
                                        const float4* __restrict__ ew4,
                                        const float* __restrict__ feat,
                                        int q, float acc[16][VEC]) {
    int2 rec = sc[e];
    float4 w = ew4[e];
    int sender = act ? rec.x : 0;
    float wx0 = act ? w.x : 0.f;
    float wx1 = act ? w.y : 0.f;
    float fy = w.z;
    int ix = rec.y >> 2, iy = rec.y & 3;
    float wy0 = 1.f - fy, wy1 = fy;
    float wxv[4], wyv[4];
#pragma unroll
    for (int c = 0; c < 4; ++c) {
        wxv[c] = (c == ix) ? wx0 : ((c == ix + 1) ? wx1 : 0.f);
        wyv[c] = (c == iy) ? wy0 : ((c == iy + 1) ? wy1 : 0.f);
    }
    float f[VEC];
    const float* fp = feat + (size_t)sender * CIN + q * VEC;
    if constexpr (VEC == 4) {
        float4 v = *(const float4*)fp;
        f[0] = v.x; f[1] = v.y; f[2] = v.z; f[3] = v.w;
    } else {
        float2 v = *(const float2*)fp;
        f[0] = v.x; f[1] = v.y;
    }
#pragma unroll
    for (int cx = 0; cx < 4; ++cx) {
        float wxc = wxv[cx];
#pragma unroll
        for (int cy = 0; cy < 4; ++cy) {
            float wc = wxc * wyv[cy];
#pragma unroll
            for (int j = 0; j < VEC; ++j)
                acc[cx * 4 + cy][j] = fmaf(wc, f[j], acc[cx * 4 + cy][j]);
        }
    }
}

// ===========================================================================
// Fused cconv layer, MFMA phase 2.
// Phase 1: register accumulation of S rows (unchanged).
// Handoff: S -> LDS as bf16 [16][M+8] (pad 8 -> 2-way bank alias, free).
// Phase 2: mfma_f32_16x16x32_bf16. A-fragment: lane l reads 8 bf16 from
// S_bf[l&15][ks*32+(l>>4)*8] (one ds_read_b128). B-fragment: one coalesced
// 16B load from fragment-packed Wp. COUT=64: wave w = colblock w, full K, no
// reduction. COUT=32: wave (w&1)=colblock, (w>>1)=K-half, pair-reduce in LDS.
// GEMM VALU work ~160 instr/wave vs ~6000 in the fp32 version (r15: the
// fused kernel was VALU-issue-bound at 72% busy).
// ===========================================================================
template <int CIN, int COUT>
__global__ __launch_bounds__(256, 4) void fused_layer(const float* __restrict__ feat,
                                                      const int2* __restrict__ sc,
                                                      const float4* __restrict__ ew4,
                                                      const int* __restrict__ rowptr,
                                                      const unsigned short* __restrict__ Wp,
                                                      const float* __restrict__ a,
                                                      float* __restrict__ P) {
    constexpr int RB = 16;            // receivers per block
    constexpr int M = 16 * CIN;       // GEMM K dimension
    constexpr int LDB = M + 8;        // bf16 row stride (pad 8)
    constexpr int nKS = M / 32;       // MFMA K-steps
    constexpr int VEC = CIN / 16;
    constexpr int CT = COUT / 16;     // colblocks (4 or 2)
    __shared__ short S_bf[RB * LDB];
    __shared__ float Rred[CT == 2 ? 512 : 4];

    int tid = threadIdx.x;
    int lane = tid & 63;
    int wave = tid >> 6;
    int slot = lane >> 4;
    int q = lane & 15;
    int rloc = wave * 4 + slot;
    int rglob = blockIdx.x * RB + rloc;
    int rs = rowptr[rglob];
    int deg = rowptr[rglob + 1] - rs;
    int md = deg;
    md = max(md, __shfl_xor(md, 16));
    md = max(md, __shfl_xor(md, 32));

    float acc[16][VEC];
#pragma unroll
    for (int cc = 0; cc < 16; ++cc)
#pragma unroll
        for (int j = 0; j < VEC; ++j) acc[cc][j] = 0.f;

#pragma unroll 2
    for (int k = 0; k < md; ++k) {
        bool act = k < deg;
        do_edge<CIN, VEC>(act, rs + (act ? k : 0), sc, ew4, feat, q, acc);
    }

    // --- handoff: acc -> bf16 LDS rows ---
    {
        short* srow = &S_bf[rloc * LDB + q * VEC];
#pragma unroll
        for (int cc = 0; cc < 16; ++cc) {
            if constexpr (VEC == 4) {
                unsigned lo = (unsigned)f2bf(acc[cc][0]) | ((unsigned)f2bf(acc[cc][1]) << 16);
                unsigned hi = (unsigned)f2bf(acc[cc][2]) | ((unsigned)f2bf(acc[cc][3]) << 16);
                *(uint2*)(srow + cc * CIN) = make_uint2(lo, hi);
            } else {
                unsigned lo = (unsigned)f2bf(acc[cc][0]) | ((unsigned)f2bf(acc[cc][1]) << 16);
                *(unsigned*)(srow + cc * CIN) = lo;
            }
        }
    }
    __syncthreads();

    // --- phase 2: MFMA GEMM ---
    int row16 = lane & 15;
    int kgrp = lane >> 4;
    f32x4 c = {0.f, 0.f, 0.f, 0.f};
    int cb, ks0;
    constexpr int KS_PER = (CT == 4) ? nKS : nKS / 2;
    if constexpr (CT == 4) { cb = wave; ks0 = 0; }
    else { cb = wave & 1; ks0 = (wave >> 1) * KS_PER; }

    const short* abase = &S_bf[row16 * LDB + kgrp * 8];
    const bf16x8* wfrag = (const bf16x8*)Wp;
    size_t wbase = (size_t)(cb * nKS + ks0) * 64 + lane;
#pragma unroll 8
    for (int kk = 0; kk < KS_PER; ++kk) {
        bf16x8 af = *(const bf16x8*)(abase + (size_t)(ks0 + kk) * 32);
        bf16x8 bf = wfrag[wbase + (size_t)kk * 64];
        c = __builtin_amdgcn_mfma_f32_16x16x32_bf16(af, bf, c, 0, 0, 0);
    }

    // --- write out (COUT=32: pair-reduce K-halves first) ---
    if constexpr (CT == 2) {
        if (wave >= 2) {
#pragma unroll
            for (int i = 0; i < 4; ++i)
                Rred[cb * 256 + (kgrp * 4 + i) * 16 + row16] = c[i];
        }
        __syncthreads();
        if (wave < 2) {
#pragma unroll
            for (int i = 0; i < 4; ++i) {
                int row = kgrp * 4 + i;
                int n = blockIdx.x * RB + row;
                float v = c[i] + Rred[cb * 256 + row * 16 + row16];
                P[(size_t)n * COUT + cb * 16 + row16] = a[n] * v;
            }
        }
    } else {
#pragma unroll
        for (int i = 0; i < 4; ++i) {
            int row = kgrp * 4 + i;
            int n = blockIdx.x * RB + row;
            P[(size_t)n * COUT + cb * 16 + row16] = a[n] * c[i];
        }
    }
}

// ===========================================================================
// BatchNorm: coalesced two-stage deterministic reduction.
// ===========================================================================
template <int COUT>
__global__ __launch_bounds__(256) void stats_part_kernel(const float* __restrict__ P,
                                                         float* __restrict__ part) {
    constexpr int RR = NPTS / 64;        // 625 rows per block
    constexpr int RSTEP = 256 / COUT;    // rows per iteration
    __shared__ float ls[256], ls2[256];
    int tid = threadIdx.x;
    int d = tid % COUT;
    int rr = tid / COUT;
    int n0 = blockIdx.x * RR;
    int n1 = n0 + RR;
    float s = 0.f, s2 = 0.f;
    for (int n = n0 + rr; n < n1; n += RSTEP) {
        float v = P[(size_t)n * COUT + d];
        s += v;
        s2 += v * v;
    }
    ls[tid] = s; ls2[tid] = s2;
    __syncthreads();
    if (tid < COUT) {
        for (int k = 1; k < RSTEP; ++k) {
            s += ls[tid + k * COUT];
            s2 += ls2[tid + k * COUT];
        }
        part[blockIdx.x * 2 * COUT + d] = s;
        part[blockIdx.x * 2 * COUT + COUT + d] = s2;
    }
}

template <int COUT>
__global__ void finalize_bn_kernel(const float* __restrict__ part,
                                   const float* __restrict__ g,
                                   const float* __restrict__ b,
                                   float* __restrict__ scb) {
    int d = threadIdx.x;
    float s = 0.f, s2 = 0.f;
    for (int k = 0; k < 64; ++k) {
        s += part[k * 2 * COUT + d];
        s2 += part[k * 2 * COUT + COUT + d];
    }
    float mean = s / (float)NPTS;
    float var = s2 / (float)NPTS - mean * mean;
    float inv = rsqrtf(var + BN_EPS);
    float scale = inv * g[d];
    scb[d] = scale;
    scb[COUT + d] = b[d] - mean * scale;
}

template <int COUT>
__global__ void apply_relu_kernel(float* __restrict__ P, const float* __restrict__ scb) {
    int t = blockIdx.x * blockDim.x + threadIdx.x;
    if (t >= NPTS * COUT) return;
    int d = t % COUT;
    float v = P[t] * scb[d] + scb[COUT + d];
    P[t] = fmaxf(v, 0.0f);
}

__global__ void apply_sigmix_kernel(const float* __restrict__ P,
                                    const float* __restrict__ scb,
                                    const float* __restrict__ x,
                                    const float* __restrict__ y,
                                    float* __restrict__ out) {
    int t = blockIdx.x * blockDim.x + threadIdx.x;
    if (t >= NPTS * 32) return;
    int d = t & 31;
    float v = P[t] * scb[d] + scb[32 + d];
    float w = 1.0f / (1.0f + expf(-v));
    out[t] = 2.0f * x[t] * w + 2.0f * y[t] * (1.0f - w);
}

// ===========================================================================
template <int CIN, int COUT>
static void run_layer(const float* feat, const int2* sc, const float4* ew4,
                      const int* rowptr, const unsigned short* Wp, const float* g,
                      const float* b, const float* a, float* part, float* scb,
                      float* P, hipStream_t stream) {
    fused_layer<CIN, COUT><<<NPTS / 16, 256, 0, stream>>>(feat, sc, ew4, rowptr, Wp, a, P);
    stats_part_kernel<COUT><<<64, 256, 0, stream>>>(P, part);
    finalize_bn_kernel<COUT><<<1, COUT, 0, stream>>>(part, g, b, scb);
}

extern "C" void kernel_launch(void* const* d_in, const int* in_sizes, int n_in,
                              void* d_out, int out_size, void* d_ws, size_t ws_size,
                              hipStream_t stream) {
    const float* x = (const float*)d_in[0];
    const float* y = (const float*)d_in[1];
    const int* senders = (const int*)d_in[2];
    const int* receivers = (const int*)d_in[3];
    const float* rel_pos = (const float*)d_in[4];
    const int* ws_ptr = (const int*)d_in[5];
    const float* a = (const float*)d_in[6];
    const float* W1 = (const float*)d_in[7];
    const float* W2 = (const float*)d_in[8];
    const float* W3 = (const float*)d_in[9];
    const float* W4 = (const float*)d_in[10];
    const float* g1 = (const float*)d_in[11];
    const float* b1 = (const float*)d_in[12];
    const float* g2 = (const float*)d_in[13];
    const float* b2 = (const float*)d_in[14];
    const float* g3 = (const float*)d_in[15];
    const float* b3 = (const float*)d_in[16];
    const float* g4 = (const float*)d_in[17];
    const float* b4 = (const float*)d_in[18];

    char* ws = (char*)d_ws;
    size_t off = 0;
    auto alloc = [&](size_t bytes) -> void* {
        void* p = ws + off;
        off += (bytes + 255) & ~(size_t)255;
        return p;
    };
    int* cnt = (int*)alloc((size_t)NPTS * sizeof(int));
    int* rowptr = (int*)alloc((size_t)(NPTS + 1) * sizeof(int));
    int* cursor = (int*)alloc((size_t)NPTS * sizeof(int));
    int2* sc = (int2*)alloc((size_t)(NEDGE + 4) * sizeof(int2));
    float4* ew4 = (float4*)alloc((size_t)(NEDGE + 4) * sizeof(float4));
    float* xa = (float*)alloc((size_t)NPTS * 64 * sizeof(float));  // also P3
    float* P1 = (float*)alloc((size_t)NPTS * 64 * sizeof(float));
    float* P2 = (float*)alloc((size_t)NPTS * 32 * sizeof(float));  // also P4
    float* xo = (float*)alloc((size_t)NPTS * 32 * sizeof(float));
    float* part = (float*)alloc((size_t)64 * 2 * 64 * sizeof(float));
    float* scb = (float*)alloc(2 * 64 * sizeof(float));
    unsigned short* Wp1 = (unsigned short*)alloc((size_t)1024 * 64 * 2);
    unsigned short* Wp2 = (unsigned short*)alloc((size_t)1024 * 32 * 2);
    unsigned short* Wp3 = (unsigned short*)alloc((size_t)512 * 64 * 2);
    unsigned short* Wp4 = (unsigned short*)alloc((size_t)1024 * 32 * 2);
    (void)ws_size; (void)in_sizes; (void)n_in; (void)out_size;

    // --- W repacks into MFMA B-fragment layout ---
    pack_w_kernel<1024, 64><<<(1024 * 64) / 256, 256, 0, stream>>>(W1, Wp1);
    pack_w_kernel<1024, 32><<<(1024 * 32) / 256, 256, 0, stream>>>(W2, Wp2);
    pack_w_kernel<512, 64><<<(512 * 64) / 256, 256, 0, stream>>>(W3, Wp3);
    pack_w_kernel<1024, 32><<<(1024 * 32) / 256, 256, 0, stream>>>(W4, Wp4);

    // --- CSR build (shared by all 4 layers) ---
    hipMemsetAsync(cnt, 0, (size_t)NPTS * sizeof(int), stream);
    hist_kernel<<<(NEDGE + 255) / 256, 256, 0, stream>>>(rel_pos, receivers, ws_ptr, cnt);
    scan_kernel<<<1, 1024, 0, stream>>>(cnt, rowptr);
    hipMemsetAsync(cursor, 0, (size_t)NPTS * sizeof(int), stream);
    fill_kernel<<<(NEDGE + 255) / 256, 256, 0, stream>>>(rel_pos, receivers, senders, ws_ptr,
                                                         rowptr, cursor, sc, ew4);
    build_xa_kernel<<<(NPTS * 64 + 255) / 256, 256, 0, stream>>>(x, y, xa);

    // Layer 1: cconv(xa; W1) -> P1, relu(bn) in place
    run_layer<64, 64>(xa, sc, ew4, rowptr, Wp1, g1, b1, a, part, scb, P1, stream);
    apply_relu_kernel<64><<<(NPTS * 64 + 255) / 256, 256, 0, stream>>>(P1, scb);

    // Layer 2: cconv(P1; W2) -> P2, sigmoid-mix -> xo
    run_layer<64, 32>(P1, sc, ew4, rowptr, Wp2, g2, b2, a, part, scb, P2, stream);
    apply_sigmix_kernel<<<(NPTS * 32 + 255) / 256, 256, 0, stream>>>(P2, scb, x, y, xo);

    // Layer 3: cconv(xo; W3) -> xa (reuse), relu(bn) in place
    run_layer<32, 64>(xo, sc, ew4, rowptr, Wp3, g3, b3, a, part, scb, xa, stream);
    apply_relu_kernel<64><<<(NPTS * 64 + 255) / 256, 256, 0, stream>>>(xa, scb);

    // Layer 4: cconv(xa; W4) -> P2 (reuse), sigmoid-mix -> out
    run_layer<64, 32>(xa, sc, ew4, rowptr, Wp4, g4, b4, a, part, scb, P2, stream);
    apply_sigmix_kernel<<<(NPTS * 32 + 255) / 256, 256, 0, stream>>>(P2, scb, x, y, (float*)d_out);
}